// Round 2
// baseline (192.814 us; speedup 1.0000x reference)
//
#include <hip/hip_runtime.h>
#include <hip/hip_bf16.h>
#include <stdint.h>

typedef __attribute__((ext_vector_type(8))) short short8;
typedef __attribute__((ext_vector_type(4))) float float4v;
typedef __attribute__((ext_vector_type(4))) unsigned short ushort4v;
typedef __attribute__((ext_vector_type(4))) unsigned int uint4v;

#define Bq 2
#define Sq 2048
#define Dq 1024
#define Hq 16
#define HDq 64

// 0.125 * log2(e): folded into Q at the QKV-GEMM epilogue so attention can use
// exp2 directly with no per-score scaling.
#define QSCALE 0.18033688011112042f

__device__ __forceinline__ unsigned short f2bf(float f) {
  union { float f; uint32_t u; } v; v.f = f;
  uint32_t r = (v.u + 0x7FFFu + ((v.u >> 16) & 1u)) >> 16;
  return (unsigned short)r;
}

// packed f32x2 -> bf16x2 (v_cvt_pk_bf16_f32 on gfx950)
__device__ __forceinline__ uint32_t pk2bf(float a, float b) {
  union { __hip_bfloat162 h; uint32_t u; } cv;
  cv.h = __float22bfloat162_rn(make_float2(a, b));
  return cv.u;
}

// async global->LDS, 16B per lane; LDS dest is wave-uniform base + lane*16.
__device__ __forceinline__ void gl_lds16(const unsigned short* g, unsigned short* l) {
  __builtin_amdgcn_global_load_lds(
      (const __attribute__((address_space(1))) void*)g,
      (__attribute__((address_space(3))) void*)l, 16, 0, 0);
}

// One launch: x (blocks 0..4095) + 4 weights (blocks 4096..8191, contiguous dst).
__global__ __launch_bounds__(256) void cvt_all_kernel(
    const float* __restrict__ x,
    const float* __restrict__ w0, const float* __restrict__ w1,
    const float* __restrict__ w2, const float* __restrict__ w3,
    unsigned short* __restrict__ xb, unsigned short* __restrict__ wb) {
  const int bid = blockIdx.x;
  const float* src;
  unsigned short* dst;
  int idx;
  if (bid < 4096) {
    src = x; dst = xb;
    idx = bid * 256 + threadIdx.x;
  } else {
    int j = (bid - 4096) * 256 + threadIdx.x;  // float4 index across 4 weights
    int z = j >> 18;                           // 262144 float4 per weight
    src = (z == 0) ? w0 : (z == 1) ? w1 : (z == 2) ? w2 : w3;
    dst = wb + (size_t)z * 1048576;            // 1M shorts per weight
    idx = j & 262143;
  }
  float4v f = ((const float4v*)src)[idx];
  ushort4v o;
#pragma unroll
  for (int q = 0; q < 4; q++) o[q] = f2bf(f[q]);
  ((ushort4v*)dst)[idx] = o;
}

// C = A(bf16 MxK) @ W^T. MT x 128 tile, BK=64, global_load_lds staging.
// LDS layout XOR-swizzled on 16B granules (phys_g = g ^ (row&7)): at 128B row
// stride unswizzled b128 frag reads are 16-way bank conflicts; swizzled 2-way
// (free). Staging side absorbs the swizzle in the precomputed global address.
// QKV epilogue scales Q (z==0) by QSCALE in fp32 before bf16 rounding.
template <bool OUTPROJ, int MT>
__global__ __launch_bounds__(256) void gemm_bt_kernel(
    const unsigned short* __restrict__ A,
    const unsigned short* __restrict__ W0,
    const unsigned short* __restrict__ W1,
    const unsigned short* __restrict__ W2,
    unsigned short* __restrict__ q_dst,
    unsigned short* __restrict__ k_dst,
    unsigned short* __restrict__ v_dst,
    float* __restrict__ f_dst,
    const float* __restrict__ bias) {
  constexpr int K = 1024;
  constexpr int NMB = MT / 32;    // 16-row m-blocks per wave
  constexpr int APASS = MT / 32;  // staging passes for A (32 rows each)
  const int z = blockIdx.z;
  const unsigned short* W = (z == 0) ? W0 : (z == 1) ? W1 : W2;
  unsigned short* qkv = (z == 0) ? q_dst : (z == 1) ? k_dst : v_dst;

  __shared__ unsigned short Asm[MT * 64];
  __shared__ unsigned short Bsm[128 * 64];

  const int t = threadIdx.x;
  const int wave = t >> 6, lane = t & 63;
  const int quad = lane >> 4, l16 = lane & 15;
  const int wy = wave >> 1, wx = wave & 1;
  const int row0 = blockIdx.x * MT;
  const int col0 = blockIdx.y * 128;

  float4v zero = {0.f, 0.f, 0.f, 0.f};
  float4v acc[NMB][4];
#pragma unroll
  for (int i = 0; i < NMB; i++)
#pragma unroll
    for (int j = 0; j < 4; j++) acc[i][j] = zero;

  // staging geometry: pass i covers rows i*32..i*32+31; thread t -> row i*32+(t>>3),
  // phys granule t&7, logical granule (t&7)^((t>>3)&7). LDS slot = i*2048 + t*8.
  const int srow = t >> 3;
  const int sgl = ((t & 7) ^ (srow & 7)) << 3;  // logical col in shorts
  const unsigned short* gA[APASS];
  const unsigned short* gB[4];
#pragma unroll
  for (int i = 0; i < APASS; i++)
    gA[i] = A + (size_t)(row0 + i * 32 + srow) * K + sgl;
#pragma unroll
  for (int i = 0; i < 4; i++)
    gB[i] = W + (size_t)(col0 + i * 32 + srow) * K + sgl;

  const int swl = (l16 & 7);  // frag-read swizzle key

  for (int k0 = 0; k0 < K; k0 += 64) {
#pragma unroll
    for (int i = 0; i < APASS; i++) gl_lds16(gA[i] + k0, &Asm[i * 2048 + t * 8]);
#pragma unroll
    for (int i = 0; i < 4; i++) gl_lds16(gB[i] + k0, &Bsm[i * 2048 + t * 8]);
    __syncthreads();
    short8 af[NMB][2], bf[4][2];
#pragma unroll
    for (int ks = 0; ks < 2; ks++) {
#pragma unroll
      for (int mb = 0; mb < NMB; mb++) {
        int row = wy * (MT / 2) + mb * 16 + l16;
        int pg = (ks * 4 + quad) ^ swl;
        af[mb][ks] = *(const short8*)(&Asm[row * 64 + pg * 8]);
      }
#pragma unroll
      for (int nb = 0; nb < 4; nb++) {
        int row = wx * 64 + nb * 16 + l16;
        int pg = (ks * 4 + quad) ^ swl;
        bf[nb][ks] = *(const short8*)(&Bsm[row * 64 + pg * 8]);
      }
    }
#pragma unroll
    for (int ks = 0; ks < 2; ks++)
#pragma unroll
      for (int mb = 0; mb < NMB; mb++)
#pragma unroll
        for (int nb = 0; nb < 4; nb++)
          acc[mb][nb] = __builtin_amdgcn_mfma_f32_16x16x32_bf16(af[mb][ks], bf[nb][ks], acc[mb][nb], 0, 0, 0);
    __syncthreads();
  }

  const float qsc = (!OUTPROJ && z == 0) ? QSCALE : 1.0f;
#pragma unroll
  for (int mb = 0; mb < NMB; mb++) {
#pragma unroll
    for (int nb = 0; nb < 4; nb++) {
#pragma unroll
      for (int r = 0; r < 4; r++) {
        int row = row0 + wy * (MT / 2) + mb * 16 + quad * 4 + r;  // token index
        int o = col0 + wx * 64 + nb * 16 + l16;                   // output feature
        float val = acc[mb][nb][r];
        if (OUTPROJ) {
          f_dst[(size_t)row * 1024 + o] = val + bias[o];
        } else {
          int b = row >> 11, s = row & 2047;
          int h = o >> 6, hd = o & 63;
          qkv[(size_t)((b * Hq + h) * Sq + s) * HDq + hd] = f2bf(val * qsc);
        }
      }
    }
  }
}

// Flash attention v3: LDS-traffic-minimized decomposition.
// 4 waves = 2 q-groups x 2 key-groups; each wave owns 64 q x 64 keys (two
// 32-key substeps). LDS reads/tile = (#q-groups) x 32KB = 64KB (was 256KB):
// key-slices are read once per q-group instead of once per wave.
// K staged via global_load_lds with GEMM-style XOR swizzle (async, zero VALU,
// zero staging regs); V reg-prefetched + v_perm packed to sigma-permuted
// [hd][key] layout. K+V double-buffered -> single barrier per tile.
// Epilogue: one-time LDS combine of the 2 key-group partials (of, dsum).
__global__ __launch_bounds__(256) void attn_kernel(
    const unsigned short* __restrict__ Q,
    const unsigned short* __restrict__ Kg,
    const unsigned short* __restrict__ Vg,
    unsigned short* __restrict__ ctx) {
  constexpr int VSTR = 136;   // Vsm stride (shorts)
  constexpr int KBUF = 8192;  // shorts per K buffer (128 x 64, swizzled linear)
  constexpr int VBUF = 8704;  // shorts per V buffer (64 x 136)
  __shared__ __align__(16) unsigned char smem[67584];
  unsigned short* Ksm = (unsigned short*)smem;            // [2][8192]
  unsigned short* Vsm = (unsigned short*)(smem + 32768);  // [2][8704]
  float* obuf = (float*)smem;                             // combine: [2][64 hd][68 q]
  float* dbuf = (float*)(smem + 34816);                   // combine: [128]

  const int bh = blockIdx.y;
  const int q0 = blockIdx.x * 128;
  const int t = threadIdx.x;
  const int wave = t >> 6, lane = t & 63;
  const int quad = lane >> 4, l16 = lane & 15;
  const int wq = wave >> 1, wk = wave & 1;
  const int swl = l16 & 7;

  const unsigned short* Qb = Q + (size_t)bh * Sq * HDq;
  const unsigned short* Kb = Kg + (size_t)bh * Sq * HDq;
  const unsigned short* Vb = Vg + (size_t)bh * Sq * HDq;

  // Q fragments: wave's 64 q rows (B-operand of QK^T S^T-trick MFMA)
  short8 qf[4][2];
#pragma unroll
  for (int qb = 0; qb < 4; qb++)
#pragma unroll
    for (int ks = 0; ks < 2; ks++)
      qf[qb][ks] = *(const short8*)(Qb + (size_t)(q0 + wq * 64 + qb * 16 + l16) * HDq + ks * 32 + quad * 8);

  short8 ones;
#pragma unroll
  for (int j = 0; j < 8; j++) ones[j] = (short)0x3F80;  // bf16 1.0

  float4v zero = {0.f, 0.f, 0.f, 0.f};
  float4v of[4][4];
  float4v dsum[4];
#pragma unroll
  for (int qb = 0; qb < 4; qb++) {
    dsum[qb] = zero;
#pragma unroll
    for (int hb = 0; hb < 4; hb++) of[qb][hb] = zero;
  }

  // K staging via gl_lds16: 4 passes x 256 threads x 16B. Pass i covers rows
  // i*32..i*32+31; thread t -> row i*32+(t>>3), phys granule t&7, logical
  // granule (t&7)^(row&7) pre-swizzled into the global address.
  const int srow = t >> 3;
  const unsigned short* gK = Kb + (size_t)srow * 64 + (((t & 7) ^ (srow & 7)) << 3);

  // V staging: thread t covers keys vr2, vr2+1 at hd slice vc16..vc16+15.
  const int vr2 = (t & 63) * 2;
  const int vc16 = (t >> 6) << 4;
  const int sig = (vr2 & ~31) + (((vr2 >> 2) & 3) << 3) + (((vr2 >> 4) & 1) << 2) + (vr2 & 3);
  const unsigned short* gV = Vb + (size_t)vr2 * 64 + vc16;

  uint4v va0, va1, vb0, vb1;

#define VLOAD(off) do {                                            \
    const unsigned short* vp = gV + (size_t)(off) * 64;            \
    va0 = *(const uint4v*)(vp);      vb0 = *(const uint4v*)(vp + 8); \
    va1 = *(const uint4v*)(vp + 64); vb1 = *(const uint4v*)(vp + 72); \
  } while (0)

  // pack keys (vr2, vr2+1) into bf16x2 words via v_perm, sigma-permuted cols
#define VPACK(bufsel) do {                                                   \
    unsigned short* vd = &Vsm[(bufsel) * VBUF + sig];                        \
    _Pragma("unroll")                                                        \
    for (int r = 0; r < 4; r++) {                                            \
      uint32_t w0 = __builtin_amdgcn_perm(va1[r], va0[r], 0x05040100u);      \
      uint32_t w1 = __builtin_amdgcn_perm(va1[r], va0[r], 0x07060302u);      \
      *(uint32_t*)(vd + (vc16 + 2 * r) * VSTR) = w0;                         \
      *(uint32_t*)(vd + (vc16 + 2 * r + 1) * VSTR) = w1;                     \
      uint32_t x0 = __builtin_amdgcn_perm(vb1[r], vb0[r], 0x05040100u);      \
      uint32_t x1 = __builtin_amdgcn_perm(vb1[r], vb0[r], 0x07060302u);      \
      *(uint32_t*)(vd + (vc16 + 8 + 2 * r) * VSTR) = x0;                     \
      *(uint32_t*)(vd + (vc16 + 8 + 2 * r + 1) * VSTR) = x1;                 \
    }                                                                        \
  } while (0)

#define KISSUE(off, bufsel) do {                                   \
    _Pragma("unroll")                                              \
    for (int i = 0; i < 4; i++)                                    \
      gl_lds16(gK + (size_t)(off) * 64 + i * 2048,                 \
               &Ksm[(bufsel) * KBUF + i * 2048 + t * 8]);          \
  } while (0)

  // prologue: tile 0 into buf0; prefetch V(1); tile 1 K into buf1
  KISSUE(0, 0);
  VLOAD(0);
  VPACK(0);
  VLOAD(128);
  __syncthreads();
  KISSUE(128, 1);

  for (int kt = 0; kt < Sq; kt += 128) {
    const int cur = (kt >> 7) & 1;
#pragma unroll
    for (int p = 0; p < 2; p++) {
      const int kb0 = cur * KBUF + (wk * 64 + p * 32) * 64;
      short8 kf[2][2];
#pragma unroll
      for (int s = 0; s < 2; s++)
#pragma unroll
        for (int ks = 0; ks < 2; ks++)
          kf[s][ks] = *(const short8*)&Ksm[kb0 + (s * 16 + l16) * 64 + ((ks * 4 + quad) ^ swl) * 8];
      short8 pf[4];
#pragma unroll
      for (int qb = 0; qb < 4; qb++) {
        float4v s0 = zero, s1 = zero;
#pragma unroll
        for (int ks = 0; ks < 2; ks++) {
          s0 = __builtin_amdgcn_mfma_f32_16x16x32_bf16(kf[0][ks], qf[qb][ks], s0, 0, 0, 0);
          s1 = __builtin_amdgcn_mfma_f32_16x16x32_bf16(kf[1][ks], qf[qb][ks], s1, 0, 0, 0);
        }
        union { uint32_t u[4]; short8 v; } pw;
        pw.u[0] = pk2bf(__builtin_amdgcn_exp2f(s0[0]), __builtin_amdgcn_exp2f(s0[1]));
        pw.u[1] = pk2bf(__builtin_amdgcn_exp2f(s0[2]), __builtin_amdgcn_exp2f(s0[3]));
        pw.u[2] = pk2bf(__builtin_amdgcn_exp2f(s1[0]), __builtin_amdgcn_exp2f(s1[1]));
        pw.u[3] = pk2bf(__builtin_amdgcn_exp2f(s1[2]), __builtin_amdgcn_exp2f(s1[3]));
        pf[qb] = pw.v;
      }
#pragma unroll
      for (int qb = 0; qb < 4; qb++)
        dsum[qb] = __builtin_amdgcn_mfma_f32_16x16x32_bf16(pf[qb], ones, dsum[qb], 0, 0, 0);
      const int vbo = cur * VBUF + wk * 64 + p * 32 + quad * 8;
#pragma unroll
      for (int hb = 0; hb < 4; hb++) {
        short8 vf = *(const short8*)&Vsm[vbo + (hb * 16 + l16) * VSTR];
#pragma unroll
        for (int qb = 0; qb < 4; qb++)
          of[qb][hb] = __builtin_amdgcn_mfma_f32_16x16x32_bf16(pf[qb], vf, of[qb][hb], 0, 0, 0);
      }
    }
    if (kt + 128 < Sq) VPACK(cur ^ 1);
    if (kt + 256 < Sq) VLOAD(kt + 256);
    __syncthreads();
    if (kt + 256 < Sq) KISSUE(kt + 256, cur);
  }

  // combine the 2 key-group partials in LDS (obuf layout [wq][hd][68 q]:
  // q contiguous so of float4 (r-dim) stores are b128; stride 68 keeps align)
  if (wk == 0) {
#pragma unroll
    for (int qb = 0; qb < 4; qb++) {
#pragma unroll
      for (int hb = 0; hb < 4; hb++)
        *(float4v*)&obuf[(wq * 64 + hb * 16 + l16) * 68 + qb * 16 + quad * 4] = of[qb][hb];
      if (l16 == 0)
#pragma unroll
        for (int r = 0; r < 4; r++)
          dbuf[wq * 64 + qb * 16 + quad * 4 + r] = dsum[qb][r];
    }
  }
  __syncthreads();
  if (wk == 1) {
#pragma unroll
    for (int qb = 0; qb < 4; qb++) {
#pragma unroll
      for (int hb = 0; hb < 4; hb++) {
        float4v* pp = (float4v*)&obuf[(wq * 64 + hb * 16 + l16) * 68 + qb * 16 + quad * 4];
        float4v o = *pp;
        o += of[qb][hb];
        *pp = o;
      }
      if (l16 == 0)
#pragma unroll
        for (int r = 0; r < 4; r++)
          dbuf[wq * 64 + qb * 16 + quad * 4 + r] += dsum[qb][r];
    }
  }
  __syncthreads();

  // final store: thread t -> q row (t&127), hd half (t>>7)*32
  const int b = bh >> 4, h = bh & 15;
  const int qq = t & 127, hseg = t >> 7;
  const float dinv = 1.0f / dbuf[qq];
  const float* ob = &obuf[(qq >> 6) * 4352 + (hseg * 32) * 68 + (qq & 63)];
  unsigned short* cp = ctx + ((size_t)(b * Sq + q0 + qq)) * Dq + h * 64 + hseg * 32;
#pragma unroll
  for (int g = 0; g < 4; g++) {
    short8 o8;
#pragma unroll
    for (int j = 0; j < 8; j++) o8[j] = (short)f2bf(ob[(g * 8 + j) * 68] * dinv);
    *(short8*)(cp + g * 8) = o8;
  }
#undef VLOAD
#undef VPACK
#undef KISSUE
}

extern "C" void kernel_launch(void* const* d_in, const int* in_sizes, int n_in,
                              void* d_out, int out_size, void* d_ws, size_t ws_size,
                              hipStream_t stream) {
  (void)in_sizes; (void)n_in; (void)out_size; (void)ws_size;
  const float* x  = (const float*)d_in[0];
  const float* wq = (const float*)d_in[1];
  const float* wk = (const float*)d_in[2];
  const float* wv = (const float*)d_in[3];
  const float* wo = (const float*)d_in[4];
  const float* bo = (const float*)d_in[5];
  float* out = (float*)d_out;

  char* ws = (char*)d_ws;
  const size_t MB = 1u << 20;
  unsigned short* xb  = (unsigned short*)(ws + 0 * MB);   // 8 MB  (4096x1024 bf16)
  unsigned short* wqb = (unsigned short*)(ws + 8 * MB);   // 2 MB each, contiguous
  unsigned short* wkb = (unsigned short*)(ws + 10 * MB);
  unsigned short* wvb = (unsigned short*)(ws + 12 * MB);
  unsigned short* wob = (unsigned short*)(ws + 14 * MB);
  unsigned short* qb  = (unsigned short*)(ws + 16 * MB);  // 8 MB  (B,H,S,HD), pre-scaled
  unsigned short* kb  = (unsigned short*)(ws + 24 * MB);  // 8 MB
  unsigned short* vb  = (unsigned short*)(ws + 32 * MB);  // 8 MB
  unsigned short* cxb = (unsigned short*)(ws + 40 * MB);  // 8 MB  (B,S,D)

  cvt_all_kernel<<<8192, 256, 0, stream>>>(x, wq, wk, wv, wo, xb, wqb);

  gemm_bt_kernel<false, 128><<<dim3(32, 8, 3), 256, 0, stream>>>(
      xb, wqb, wkb, wvb, qb, kb, vb, nullptr, nullptr);
  attn_kernel<<<dim3(16, 32), 256, 0, stream>>>(qb, kb, vb, cxb);
  gemm_bt_kernel<true, 64><<<dim3(64, 8, 1), 256, 0, stream>>>(
      cxb, wob, wob, wob, nullptr, nullptr, nullptr, out, bo);
}

// Round 4
// 184.224 us; speedup vs baseline: 1.0466x; 1.0466x over previous
//
#include <hip/hip_runtime.h>
#include <hip/hip_bf16.h>
#include <stdint.h>

typedef __attribute__((ext_vector_type(8))) short short8;
typedef __attribute__((ext_vector_type(4))) float float4v;
typedef __attribute__((ext_vector_type(4))) unsigned short ushort4v;

#define Bq 2
#define Sq 2048
#define Dq 1024
#define Hq 16
#define HDq 64

// 0.125 * log2(e): folded into Q at the QKV-GEMM epilogue so attention can use
// exp2 directly with no per-score scaling.
#define QSCALE 0.18033688011112042f

__device__ __forceinline__ unsigned short f2bf(float f) {
  union { float f; uint32_t u; } v; v.f = f;
  uint32_t r = (v.u + 0x7FFFu + ((v.u >> 16) & 1u)) >> 16;
  return (unsigned short)r;
}

// packed f32x2 -> bf16x2 (v_cvt_pk_bf16_f32 on gfx950)
__device__ __forceinline__ uint32_t pk2bf(float a, float b) {
  union { __hip_bfloat162 h; uint32_t u; } cv;
  cv.h = __float22bfloat162_rn(make_float2(a, b));
  return cv.u;
}

// async global->LDS, 16B per lane; LDS dest is wave-uniform base + lane*16.
__device__ __forceinline__ void gl_lds16(const unsigned short* g, unsigned short* l) {
  __builtin_amdgcn_global_load_lds(
      (const __attribute__((address_space(1))) void*)g,
      (__attribute__((address_space(3))) void*)l, 16, 0, 0);
}

// One launch: x (blocks 0..4095) + 4 weights (blocks 4096..8191, contiguous dst).
__global__ __launch_bounds__(256) void cvt_all_kernel(
    const float* __restrict__ x,
    const float* __restrict__ w0, const float* __restrict__ w1,
    const float* __restrict__ w2, const float* __restrict__ w3,
    unsigned short* __restrict__ xb, unsigned short* __restrict__ wb) {
  const int bid = blockIdx.x;
  const float* src;
  unsigned short* dst;
  int idx;
  if (bid < 4096) {
    src = x; dst = xb;
    idx = bid * 256 + threadIdx.x;
  } else {
    int j = (bid - 4096) * 256 + threadIdx.x;  // float4 index across 4 weights
    int z = j >> 18;                           // 262144 float4 per weight
    src = (z == 0) ? w0 : (z == 1) ? w1 : (z == 2) ? w2 : w3;
    dst = wb + (size_t)z * 1048576;            // 1M shorts per weight
    idx = j & 262143;
  }
  float4v f = ((const float4v*)src)[idx];
  ushort4v o;
#pragma unroll
  for (int q = 0; q < 4; q++) o[q] = f2bf(f[q]);
  ((ushort4v*)dst)[idx] = o;
}

// C = A(bf16 MxK) @ W^T. MT x 128 tile, BK=64, global_load_lds staging.
// LDS layout XOR-swizzled on 16B granules (phys_g = g ^ (row&7)): at 128B row
// stride unswizzled b128 frag reads are 16-way bank conflicts; swizzled 2-way
// (free). Staging side absorbs the swizzle in the precomputed global address.
// QKV epilogue scales Q (z==0) by QSCALE in fp32 before bf16 rounding.
template <bool OUTPROJ, int MT>
__global__ __launch_bounds__(256) void gemm_bt_kernel(
    const unsigned short* __restrict__ A,
    const unsigned short* __restrict__ W0,
    const unsigned short* __restrict__ W1,
    const unsigned short* __restrict__ W2,
    unsigned short* __restrict__ q_dst,
    unsigned short* __restrict__ k_dst,
    unsigned short* __restrict__ v_dst,
    float* __restrict__ f_dst,
    const float* __restrict__ bias) {
  constexpr int K = 1024;
  constexpr int NMB = MT / 32;    // 16-row m-blocks per wave
  constexpr int APASS = MT / 32;  // staging passes for A (32 rows each)
  const int z = blockIdx.z;
  const unsigned short* W = (z == 0) ? W0 : (z == 1) ? W1 : W2;
  unsigned short* qkv = (z == 0) ? q_dst : (z == 1) ? k_dst : v_dst;

  __shared__ unsigned short Asm[MT * 64];
  __shared__ unsigned short Bsm[128 * 64];

  const int t = threadIdx.x;
  const int wave = t >> 6, lane = t & 63;
  const int quad = lane >> 4, l16 = lane & 15;
  const int wy = wave >> 1, wx = wave & 1;
  const int row0 = blockIdx.x * MT;
  const int col0 = blockIdx.y * 128;

  float4v zero = {0.f, 0.f, 0.f, 0.f};
  float4v acc[NMB][4];
#pragma unroll
  for (int i = 0; i < NMB; i++)
#pragma unroll
    for (int j = 0; j < 4; j++) acc[i][j] = zero;

  // staging geometry: pass i covers rows i*32..i*32+31; thread t -> row i*32+(t>>3),
  // phys granule t&7, logical granule (t&7)^((t>>3)&7). LDS slot = i*2048 + t*8.
  const int srow = t >> 3;
  const int sgl = ((t & 7) ^ (srow & 7)) << 3;  // logical col in shorts
  const unsigned short* gA[APASS];
  const unsigned short* gB[4];
#pragma unroll
  for (int i = 0; i < APASS; i++)
    gA[i] = A + (size_t)(row0 + i * 32 + srow) * K + sgl;
#pragma unroll
  for (int i = 0; i < 4; i++)
    gB[i] = W + (size_t)(col0 + i * 32 + srow) * K + sgl;

  const int swl = (l16 & 7);  // frag-read swizzle key

  for (int k0 = 0; k0 < K; k0 += 64) {
#pragma unroll
    for (int i = 0; i < APASS; i++) gl_lds16(gA[i] + k0, &Asm[i * 2048 + t * 8]);
#pragma unroll
    for (int i = 0; i < 4; i++) gl_lds16(gB[i] + k0, &Bsm[i * 2048 + t * 8]);
    __syncthreads();
    short8 af[NMB][2], bf[4][2];
#pragma unroll
    for (int ks = 0; ks < 2; ks++) {
#pragma unroll
      for (int mb = 0; mb < NMB; mb++) {
        int row = wy * (MT / 2) + mb * 16 + l16;
        int pg = (ks * 4 + quad) ^ swl;
        af[mb][ks] = *(const short8*)(&Asm[row * 64 + pg * 8]);
      }
#pragma unroll
      for (int nb = 0; nb < 4; nb++) {
        int row = wx * 64 + nb * 16 + l16;
        int pg = (ks * 4 + quad) ^ swl;
        bf[nb][ks] = *(const short8*)(&Bsm[row * 64 + pg * 8]);
      }
    }
#pragma unroll
    for (int ks = 0; ks < 2; ks++)
#pragma unroll
      for (int mb = 0; mb < NMB; mb++)
#pragma unroll
        for (int nb = 0; nb < 4; nb++)
          acc[mb][nb] = __builtin_amdgcn_mfma_f32_16x16x32_bf16(af[mb][ks], bf[nb][ks], acc[mb][nb], 0, 0, 0);
    __syncthreads();
  }

  const float qsc = (!OUTPROJ && z == 0) ? QSCALE : 1.0f;
#pragma unroll
  for (int mb = 0; mb < NMB; mb++) {
#pragma unroll
    for (int nb = 0; nb < 4; nb++) {
#pragma unroll
      for (int r = 0; r < 4; r++) {
        int row = row0 + wy * (MT / 2) + mb * 16 + quad * 4 + r;  // token index
        int o = col0 + wx * 64 + nb * 16 + l16;                   // output feature
        float val = acc[mb][nb][r];
        if (OUTPROJ) {
          f_dst[(size_t)row * 1024 + o] = val + bias[o];
        } else {
          int b = row >> 11, s = row & 2047;
          int h = o >> 6, hd = o & 63;
          qkv[(size_t)((b * Hq + h) * Sq + s) * HDq + hd] = f2bf(val * qsc);
        }
      }
    }
  }
}

// Flash attention v5: v4's decomposition, verified building blocks only.
// 512 threads, 8 waves = 4 q-groups x 2 key-groups; each wave 32q x 64keys.
// Per-wave LDS reads/tile = 8 b128 (K) + 8 b128 (V) — half of v2 — at 16
// waves/CU (2 blocks) = 4 waves/SIMD (v2-level occupancy).
// K: global_load_lds with GEMM-style XOR swizzle (verified path, bit-identical
// addressing to gemm_bt_kernel). V: v2's verified reg-prefetch + v_perm pack
// into sigma-permuted [hd][key] layout (VSTR=136). K+V double-buffered ->
// one barrier per tile. Epilogue: v3's verified wk-partial combine in LDS.
__global__ __launch_bounds__(512, 4) void attn_kernel(
    const unsigned short* __restrict__ Q,
    const unsigned short* __restrict__ Kg,
    const unsigned short* __restrict__ Vg,
    unsigned short* __restrict__ ctx) {
  constexpr int VSTR = 136;   // Vsm stride (shorts)
  constexpr int KBUF = 8192;  // shorts per K buffer (128 keys x 64 hd, swizzled)
  constexpr int VBUF = 8704;  // shorts per V buffer (64 x 136)
  constexpr int QSTR = 132;   // obuf q-dim stride (f32)
  __shared__ __align__(16) unsigned char smem[67584];
  unsigned short* Ksm = (unsigned short*)smem;            // [2][8192]
  unsigned short* Vsm = (unsigned short*)(smem + 32768);  // [2][8704]
  float* obuf = (float*)smem;                             // combine: [64 hd][132 q]
  float* dbuf = (float*)(smem + 33792);                   // combine: [128]

  const int bh = blockIdx.y;
  const int q0 = blockIdx.x * 128;
  const int t = threadIdx.x;
  const int wave = t >> 6, lane = t & 63;
  const int quad = lane >> 4, l16 = lane & 15;
  const int wq = wave >> 1, wk = wave & 1;
  const int swl = l16 & 7;

  const unsigned short* Qb = Q + (size_t)bh * Sq * HDq;
  const unsigned short* Kb = Kg + (size_t)bh * Sq * HDq;
  const unsigned short* Vb = Vg + (size_t)bh * Sq * HDq;

  // Q fragments: wave's 32 q rows (B-operand of QK^T S^T-trick MFMA)
  short8 qf[2][2];
#pragma unroll
  for (int qb = 0; qb < 2; qb++)
#pragma unroll
    for (int ks = 0; ks < 2; ks++)
      qf[qb][ks] = *(const short8*)(Qb + (size_t)(q0 + wq * 32 + qb * 16 + l16) * HDq + ks * 32 + quad * 8);

  short8 ones;
#pragma unroll
  for (int j = 0; j < 8; j++) ones[j] = (short)0x3F80;  // bf16 1.0

  float4v zero = {0.f, 0.f, 0.f, 0.f};
  float4v of[2][4];   // [qb][hb]; D layout row=q (quad*4+r), col=hd (l16)
  float4v dsum[2];
#pragma unroll
  for (int qb = 0; qb < 2; qb++) {
    dsum[qb] = zero;
#pragma unroll
    for (int hb = 0; hb < 4; hb++) of[qb][hb] = zero;
  }

  // K staging: 2 passes x 512 threads x 16B. Pass i row = i*64 + (t>>3);
  // XOR swizzle on 16B granules pre-applied to the global address.
  const int srow = t >> 3;
  const unsigned short* gK = Kb + (size_t)srow * 64 + (((t & 7) ^ (srow & 7)) << 3);

  // V staging (v2-verified): thread t covers keys vr2, vr2+1 at hd slice
  // vc8..vc8+7 (wave-indexed); sigma permutes key -> column for PV b128 frags.
  const int vr2 = (t & 63) * 2;
  const int vc8 = (t >> 6) << 3;
  const int sig = (vr2 & ~31) + (((vr2 >> 2) & 3) << 3) + (((vr2 >> 4) & 1) << 2) + (vr2 & 3);
  const unsigned short* gV = Vb + (size_t)vr2 * HDq + vc8;

  short8 vpr0, vpr1;

#define VLOAD(off) do {                                              \
    const unsigned short* vp = gV + (size_t)(off) * HDq;             \
    vpr0 = *(const short8*)(vp);                                     \
    vpr1 = *(const short8*)(vp + HDq);                               \
  } while (0)

#define VPACK(bufsel) do {                                           \
    unsigned short* vd = &Vsm[(bufsel) * VBUF + sig];                \
    _Pragma("unroll")                                                \
    for (int j = 0; j < 8; j++) {                                    \
      uint32_t pk = (uint32_t)(unsigned short)vpr0[j] |              \
                    ((uint32_t)(unsigned short)vpr1[j] << 16);       \
      *(uint32_t*)(vd + (vc8 + j) * VSTR) = pk;                      \
    }                                                                \
  } while (0)

#define KISSUE(off, bufsel) do {                                     \
    gl_lds16(gK + (size_t)(off) * 64, &Ksm[(bufsel) * KBUF + t * 8]);\
    gl_lds16(gK + (size_t)(off) * 64 + 4096,                         \
             &Ksm[(bufsel) * KBUF + 4096 + t * 8]);                  \
  } while (0)

  // prologue: K0 async + V0 pack into buf0; barrier drains both; K1 async.
  KISSUE(0, 0);
  VLOAD(0);
  VPACK(0);
  VLOAD(128);
  __syncthreads();
  KISSUE(128, 1);

  for (int kt = 0; kt < Sq; kt += 128) {
    const int cur = (kt >> 7) & 1;
#pragma unroll
    for (int p = 0; p < 2; p++) {
      const int kb0 = cur * KBUF + wk * 4096 + p * 2048;
      short8 kf[2][2];
#pragma unroll
      for (int s = 0; s < 2; s++)
#pragma unroll
        for (int ks = 0; ks < 2; ks++)
          kf[s][ks] = *(const short8*)&Ksm[kb0 + (s * 16 + l16) * 64 + ((ks * 4 + quad) ^ swl) * 8];
      short8 pf[2];
#pragma unroll
      for (int qb = 0; qb < 2; qb++) {
        float4v sa = zero, sb = zero;
#pragma unroll
        for (int ks = 0; ks < 2; ks++) {
          sa = __builtin_amdgcn_mfma_f32_16x16x32_bf16(kf[0][ks], qf[qb][ks], sa, 0, 0, 0);
          sb = __builtin_amdgcn_mfma_f32_16x16x32_bf16(kf[1][ks], qf[qb][ks], sb, 0, 0, 0);
        }
        union { uint32_t u[4]; short8 v; } pw;
        pw.u[0] = pk2bf(__builtin_amdgcn_exp2f(sa[0]), __builtin_amdgcn_exp2f(sa[1]));
        pw.u[1] = pk2bf(__builtin_amdgcn_exp2f(sa[2]), __builtin_amdgcn_exp2f(sa[3]));
        pw.u[2] = pk2bf(__builtin_amdgcn_exp2f(sb[0]), __builtin_amdgcn_exp2f(sb[1]));
        pw.u[3] = pk2bf(__builtin_amdgcn_exp2f(sb[2]), __builtin_amdgcn_exp2f(sb[3]));
        pf[qb] = pw.v;
      }
#pragma unroll
      for (int qb = 0; qb < 2; qb++)
        dsum[qb] = __builtin_amdgcn_mfma_f32_16x16x32_bf16(pf[qb], ones, dsum[qb], 0, 0, 0);
      const int vbo = cur * VBUF + wk * 64 + p * 32 + quad * 8;
#pragma unroll
      for (int hb = 0; hb < 4; hb++) {
        short8 vf = *(const short8*)&Vsm[vbo + (hb * 16 + l16) * VSTR];
#pragma unroll
        for (int qb = 0; qb < 2; qb++)
          of[qb][hb] = __builtin_amdgcn_mfma_f32_16x16x32_bf16(pf[qb], vf, of[qb][hb], 0, 0, 0);
      }
    }
    if (kt + 128 < Sq) VPACK(cur ^ 1);
    if (kt + 256 < Sq) VLOAD(kt + 256);
    __syncthreads();
    if (kt + 256 < Sq) KISSUE(kt + 256, cur);
  }

  // combine the 2 key-group partials in LDS: obuf[hd][q] f32, float4 stores
  // along q (quad*4+r contiguous).
  if (wk == 0) {
#pragma unroll
    for (int qb = 0; qb < 2; qb++) {
#pragma unroll
      for (int hb = 0; hb < 4; hb++)
        *(float4v*)&obuf[(hb * 16 + l16) * QSTR + wq * 32 + qb * 16 + quad * 4] = of[qb][hb];
      if (l16 == 0)
#pragma unroll
        for (int r = 0; r < 4; r++)
          dbuf[wq * 32 + qb * 16 + quad * 4 + r] = dsum[qb][r];
    }
  }
  __syncthreads();
  if (wk == 1) {
#pragma unroll
    for (int qb = 0; qb < 2; qb++) {
#pragma unroll
      for (int hb = 0; hb < 4; hb++) {
        float4v* pp = (float4v*)&obuf[(hb * 16 + l16) * QSTR + wq * 32 + qb * 16 + quad * 4];
        float4v o = *pp;
        o += of[qb][hb];
        *pp = o;
      }
      if (l16 == 0)
#pragma unroll
        for (int r = 0; r < 4; r++)
          dbuf[wq * 32 + qb * 16 + quad * 4 + r] += dsum[qb][r];
    }
  }
  __syncthreads();

  // final store: thread t -> q row (t&127), 16-hd segment (t>>7)
  const int b = bh >> 4, h = bh & 15;
  const int qq = t & 127, hseg = t >> 7;
  const float dinv = 1.0f / dbuf[qq];
  unsigned short* cp = ctx + ((size_t)(b * Sq + q0 + qq)) * Dq + h * 64 + hseg * 16;
  short8 o8a, o8b;
#pragma unroll
  for (int j = 0; j < 8; j++) o8a[j] = (short)f2bf(obuf[(hseg * 16 + j) * QSTR + qq] * dinv);
#pragma unroll
  for (int j = 0; j < 8; j++) o8b[j] = (short)f2bf(obuf[(hseg * 16 + 8 + j) * QSTR + qq] * dinv);
  *(short8*)cp = o8a;
  *(short8*)(cp + 8) = o8b;
#undef VLOAD
#undef VPACK
#undef KISSUE
}

extern "C" void kernel_launch(void* const* d_in, const int* in_sizes, int n_in,
                              void* d_out, int out_size, void* d_ws, size_t ws_size,
                              hipStream_t stream) {
  (void)in_sizes; (void)n_in; (void)out_size; (void)ws_size;
  const float* x  = (const float*)d_in[0];
  const float* wq = (const float*)d_in[1];
  const float* wk = (const float*)d_in[2];
  const float* wv = (const float*)d_in[3];
  const float* wo = (const float*)d_in[4];
  const float* bo = (const float*)d_in[5];
  float* out = (float*)d_out;

  char* ws = (char*)d_ws;
  const size_t MB = 1u << 20;
  unsigned short* xb  = (unsigned short*)(ws + 0 * MB);   // 8 MB  (4096x1024 bf16)
  unsigned short* wqb = (unsigned short*)(ws + 8 * MB);   // 2 MB each, contiguous
  unsigned short* wkb = (unsigned short*)(ws + 10 * MB);
  unsigned short* wvb = (unsigned short*)(ws + 12 * MB);
  unsigned short* wob = (unsigned short*)(ws + 14 * MB);
  unsigned short* qb  = (unsigned short*)(ws + 16 * MB);  // 8 MB  (B,H,S,HD), pre-scaled
  unsigned short* kb  = (unsigned short*)(ws + 24 * MB);  // 8 MB
  unsigned short* vb  = (unsigned short*)(ws + 32 * MB);  // 8 MB
  unsigned short* cxb = (unsigned short*)(ws + 40 * MB);  // 8 MB  (B,S,D)

  cvt_all_kernel<<<8192, 256, 0, stream>>>(x, wq, wk, wv, wo, xb, wqb);

  gemm_bt_kernel<false, 128><<<dim3(32, 8, 3), 256, 0, stream>>>(
      xb, wqb, wkb, wvb, qb, kb, vb, nullptr, nullptr);
  attn_kernel<<<dim3(16, 32), 512, 0, stream>>>(qb, kb, vb, cxb);
  gemm_bt_kernel<true, 64><<<dim3(64, 8, 1), 256, 0, stream>>>(
      cxb, wob, wob, wob, nullptr, nullptr, nullptr, out, bo);
}